// Round 1
// baseline (5458.141 us; speedup 1.0000x reference)
//
#include <hip/hip_runtime.h>
#include <cstddef>
#include <cstdint>

// Problem constants
#define Bb 4
#define Tt 4096
#define Dd 1024
#define Hh 16
#define HDd 64
#define NSs 64
#define SPHh 4
#define HMm 4096
#define MTOK (Bb*Tt)   // 16384

__device__ __forceinline__ float gelu_f(float x) {
    return 0.5f * x * (1.0f + erff(x * 0.70710678118654752440f));
}

// ---------------- K0: cb[j] = sum_k slot_mean_full[k] * rw1[1024+k, j] ----------------
__global__ __launch_bounds__(128) void cb_kernel(const float* __restrict__ slot_init,
                                                 const float* __restrict__ rw1,
                                                 float* __restrict__ cb) {
    __shared__ float sm[64];
    int tid = threadIdx.x;
    if (tid < 64) {
        float s = 0.f;
        for (int i = 0; i < 64; ++i) s += slot_init[i * 64 + tid];
        sm[tid] = s * (1.0f / 64.0f);
    }
    __syncthreads();
    int j = blockIdx.x * 128 + tid;
    float acc = 0.f;
    for (int k = 0; k < 1024; ++k)
        acc = fmaf(sm[k & 63], rw1[(size_t)(1024 + k) * 1024 + j], acc);
    cb[j] = acc;
}

// ---------------- generic fp32 SGEMM: C = op(A@B + bias (+bias2)) ----------------
// A [M,K] row-major, B [K,N] row-major. BM=BN=128, BK=8, 256 threads, 8x8/thread.
template <int DO_GELU>
__global__ __launch_bounds__(256) void sgemm_k(const float* __restrict__ A,
                                               const float* __restrict__ Bw,
                                               const float* __restrict__ bias,
                                               const float* __restrict__ bias2,
                                               float* __restrict__ C,
                                               int M, int N, int K) {
    __shared__ float As[8][128];
    __shared__ float Bs[8][128];
    const int tid = threadIdx.x;
    const int brow = blockIdx.y * 128;
    const int bcol = blockIdx.x * 128;

    const int tx = (tid & 15) * 8;
    const int ty = (tid >> 4) * 8;

    const int arow = tid >> 1;
    const int acol = (tid & 1) * 4;
    const int brl  = tid >> 5;
    const int bcl  = (tid & 31) * 4;

    const float* Aptr = A + (size_t)(brow + arow) * K + acol;
    const float* Bptr = Bw + (size_t)brl * N + bcol + bcl;

    float acc[8][8] = {};

    for (int k0 = 0; k0 < K; k0 += 8) {
        float4 av = *(const float4*)(Aptr + k0);
        float4 bv = *(const float4*)(Bptr + (size_t)k0 * N);
        As[acol + 0][arow] = av.x;
        As[acol + 1][arow] = av.y;
        As[acol + 2][arow] = av.z;
        As[acol + 3][arow] = av.w;
        *(float4*)&Bs[brl][bcl] = bv;
        __syncthreads();
#pragma unroll
        for (int kk = 0; kk < 8; ++kk) {
            float a[8], b[8];
            *(float4*)&a[0] = *(const float4*)&As[kk][ty];
            *(float4*)&a[4] = *(const float4*)&As[kk][ty + 4];
            *(float4*)&b[0] = *(const float4*)&Bs[kk][tx];
            *(float4*)&b[4] = *(const float4*)&Bs[kk][tx + 4];
#pragma unroll
            for (int i = 0; i < 8; ++i)
#pragma unroll
                for (int j = 0; j < 8; ++j)
                    acc[i][j] = fmaf(a[i], b[j], acc[i][j]);
        }
        __syncthreads();
    }

#pragma unroll
    for (int i = 0; i < 8; ++i) {
        size_t row = (size_t)(brow + ty + i);
#pragma unroll
        for (int j = 0; j < 8; ++j) {
            int col = bcol + tx + j;
            float v = acc[i][j];
            if (bias)  v += bias[col];
            if (bias2) v += bias2[col];
            if (DO_GELU) v = gelu_f(v);
            C[row * N + col] = v;
        }
    }
}

// ---------------- K2: route logits, N=64: logits = (h1@rw2 + rb2) / (|tau|+0.1) -------
__global__ __launch_bounds__(256) void logits_k(const float* __restrict__ A,
                                                const float* __restrict__ Bw,
                                                const float* __restrict__ rb2,
                                                const float* __restrict__ taup,
                                                float* __restrict__ Cl,
                                                int M, int K) {
    __shared__ float As[16][64];
    __shared__ float Bs[16][64];
    const int tid = threadIdx.x;
    const int m0 = blockIdx.x * 64;
    const int tx = (tid & 15) * 4;
    const int ty = (tid >> 4) * 4;
    const int arow = tid >> 2;
    const int acol = (tid & 3) * 4;
    const int brl = tid >> 4;
    const int bcl = (tid & 15) * 4;

    float acc[4][4] = {};

    for (int k0 = 0; k0 < K; k0 += 16) {
        float4 av = *(const float4*)(A + (size_t)(m0 + arow) * K + k0 + acol);
        float4 bv = *(const float4*)(Bw + (size_t)(k0 + brl) * 64 + bcl);
        As[acol + 0][arow] = av.x;
        As[acol + 1][arow] = av.y;
        As[acol + 2][arow] = av.z;
        As[acol + 3][arow] = av.w;
        *(float4*)&Bs[brl][bcl] = bv;
        __syncthreads();
#pragma unroll
        for (int kk = 0; kk < 16; ++kk) {
            float a[4], b[4];
            *(float4*)&a[0] = *(const float4*)&As[kk][ty];
            *(float4*)&b[0] = *(const float4*)&Bs[kk][tx];
#pragma unroll
            for (int i = 0; i < 4; ++i)
#pragma unroll
                for (int j = 0; j < 4; ++j)
                    acc[i][j] = fmaf(a[i], b[j], acc[i][j]);
        }
        __syncthreads();
    }
    float inv = 1.0f / (fabsf(taup[0]) + 0.1f);
#pragma unroll
    for (int i = 0; i < 4; ++i)
#pragma unroll
        for (int j = 0; j < 4; ++j)
            Cl[(size_t)(m0 + ty + i) * 64 + tx + j] = (acc[i][j] + rb2[tx + j]) * inv;
}

// ---------------- K3: top-32-of-64 + softmax -> dense alpha ----------------
// one wave (64 lanes) per token; tie-break matches lax.top_k (lower index wins)
__global__ __launch_bounds__(256) void topk_k(const float* __restrict__ logits,
                                              float* __restrict__ alpha) {
    int wave = threadIdx.x >> 6;
    int lane = threadIdx.x & 63;
    int t = blockIdx.x * 4 + wave;
    float li = logits[(size_t)t * 64 + lane];
    // global max (top-1 is always selected, so softmax max == global max)
    float m = li;
#pragma unroll
    for (int off = 32; off; off >>= 1) m = fmaxf(m, __shfl_xor(m, off, 64));
    // rank: number of j strictly beating lane (ties -> lower index wins)
    int cnt = 0;
    for (int off = 1; off < 64; ++off) {
        int j = (lane + off) & 63;
        float lj = __shfl(li, j, 64);
        cnt += (lj > li) || (lj == li && j < lane);
    }
    float e = (cnt < 32) ? expf(li - m) : 0.0f;
    float s = e;
#pragma unroll
    for (int off = 32; off; off >>= 1) s += __shfl_xor(s, off, 64);
    alpha[(size_t)t * 64 + lane] = e / s;
}

// ---------------- K4: slot pooling (T-split partial sums) ----------------
__global__ __launch_bounds__(256) void pool_part_k(const float* __restrict__ x,
                                                   const float* __restrict__ alpha,
                                                   float* __restrict__ part,
                                                   float* __restrict__ partw) {
    int bh = blockIdx.x;   // b*16 + h
    int c = blockIdx.y;    // chunk 0..7
    int b = bh >> 4, h = bh & 15;
    int tid = threadIdx.x;
    int s = tid >> 6, d = tid & 63;
    __shared__ float lx[16][64];
    __shared__ float la[16][4];
    float acc = 0.f, wacc = 0.f;
    const int tchunk = Tt / 8;     // 512
    const int t0base = c * tchunk;
    for (int t0 = 0; t0 < tchunk; t0 += 16) {
        int ttr = tid >> 4;
        int ddr = (tid & 15) * 4;
        size_t trow = (size_t)b * Tt + t0base + t0 + ttr;
        float4 xv = *(const float4*)(x + trow * Dd + h * 64 + ddr);
        *(float4*)&lx[ttr][ddr] = xv;
        if (tid < 64) {
            int tt2 = tid >> 2, ss = tid & 3;
            la[tt2][ss] = alpha[((size_t)b * Tt + t0base + t0 + tt2) * 64 + h * 4 + ss];
        }
        __syncthreads();
#pragma unroll
        for (int q = 0; q < 16; ++q) {
            float av = la[q][s];
            acc = fmaf(av, lx[q][d], acc);
            wacc += av;
        }
        __syncthreads();
    }
    part[(((size_t)c * 64 + bh) * 4 + s) * 64 + d] = acc;
    if (d == 0) partw[((size_t)c * 64 + bh) * 4 + s] = wacc;
}

__global__ __launch_bounds__(256) void pool_comb_k(const float* __restrict__ part,
                                                   const float* __restrict__ partw,
                                                   float* __restrict__ slot_in) {
    int bh = blockIdx.x;
    int tid = threadIdx.x;
    int s = tid >> 6, d = tid & 63;
    float acc = 0.f, w = 0.f;
    for (int c = 0; c < 8; ++c) {
        acc += part[(((size_t)c * 64 + bh) * 4 + s) * 64 + d];
        w   += partw[((size_t)c * 64 + bh) * 4 + s];
    }
    slot_in[((size_t)bh * 4 + s) * 64 + d] = acc / (w + 1e-8f);
}

// ---------------- K5: GRU + slot MLP, one wave per slot ----------------
__global__ __launch_bounds__(64) void gru_k(const float* __restrict__ slot_in,
                                            const float* __restrict__ slot_init,
                                            const float* __restrict__ gwi,
                                            const float* __restrict__ gwh,
                                            const float* __restrict__ gbi,
                                            const float* __restrict__ gbh,
                                            const float* __restrict__ hpw,
                                            const float* __restrict__ hpb,
                                            const float* __restrict__ ohw,
                                            const float* __restrict__ ohb,
                                            float* __restrict__ S_new) {
    int slot = blockIdx.x;       // b*64 + (h*4+s)
    int hs = slot & 63;
    int d = threadIdx.x;
    __shared__ float si[64], hp[64], hn[64], g[256];
    si[d] = slot_in[(size_t)slot * 64 + d];
    hp[d] = slot_init[(size_t)hs * 64 + d];
    __syncthreads();
    float gi_r = gbi[d], gi_z = gbi[64 + d], gi_n = gbi[128 + d];
    float gh_r = gbh[d], gh_z = gbh[64 + d], gh_n = gbh[128 + d];
    for (int k = 0; k < 64; ++k) {
        float sv = si[k], hv = hp[k];
        gi_r = fmaf(sv, gwi[(size_t)(d) * 64 + k], gi_r);
        gi_z = fmaf(sv, gwi[(size_t)(64 + d) * 64 + k], gi_z);
        gi_n = fmaf(sv, gwi[(size_t)(128 + d) * 64 + k], gi_n);
        gh_r = fmaf(hv, gwh[(size_t)(d) * 64 + k], gh_r);
        gh_z = fmaf(hv, gwh[(size_t)(64 + d) * 64 + k], gh_z);
        gh_n = fmaf(hv, gwh[(size_t)(128 + d) * 64 + k], gh_n);
    }
    float r = 1.0f / (1.0f + expf(-(gi_r + gh_r)));
    float z = 1.0f / (1.0f + expf(-(gi_z + gh_z)));
    float n = tanhf(gi_n + r * gh_n);
    float hnew = (1.0f - z) * n + z * hp[d];
    hn[d] = hnew;
    __syncthreads();
    float p0 = hpb[d], p1 = hpb[64 + d], p2 = hpb[128 + d], p3 = hpb[192 + d];
    for (int k = 0; k < 64; ++k) {
        float hv = hn[k];
        p0 = fmaf(hv, hpw[(size_t)k * 256 + d], p0);
        p1 = fmaf(hv, hpw[(size_t)k * 256 + 64 + d], p1);
        p2 = fmaf(hv, hpw[(size_t)k * 256 + 128 + d], p2);
        p3 = fmaf(hv, hpw[(size_t)k * 256 + 192 + d], p3);
    }
    g[d] = gelu_f(p0); g[64 + d] = gelu_f(p1); g[128 + d] = gelu_f(p2); g[192 + d] = gelu_f(p3);
    __syncthreads();
    float o = ohb[d];
    for (int j = 0; j < 256; ++j) o = fmaf(g[j], ohw[(size_t)j * 64 + d], o);
    S_new[(size_t)slot * 64 + d] = o;
}

// ---------------- K6: broadcast back to tokens ----------------
__global__ __launch_bounds__(256) void bcast_k(const float* __restrict__ alpha,
                                               const float* __restrict__ S_new,
                                               float* __restrict__ out_b) {
    int t = blockIdx.x;          // global token
    int b = t >> 12;             // t / 4096
    __shared__ float a[64];
    int tid = threadIdx.x;
    if (tid < 64) a[tid] = alpha[(size_t)t * 64 + tid];
    __syncthreads();
#pragma unroll
    for (int o = tid; o < 1024; o += 256) {
        int h = o >> 6, d = o & 63;
        const float* sp = S_new + ((size_t)(b * 16 + h) * 4) * 64 + d;
        float acc = a[h * 4 + 0] * sp[0] + a[h * 4 + 1] * sp[64] +
                    a[h * 4 + 2] * sp[128] + a[h * 4 + 3] * sp[192];
        out_b[(size_t)t * 1024 + o] = acc;
    }
}

extern "C" void kernel_launch(void* const* d_in, const int* in_sizes, int n_in,
                              void* d_out, int out_size, void* d_ws, size_t ws_size,
                              hipStream_t stream) {
    const float* x         = (const float*)d_in[0];
    const float* slot_init = (const float*)d_in[1];
    const float* rw1       = (const float*)d_in[2];
    const float* rb1       = (const float*)d_in[3];
    const float* rw2       = (const float*)d_in[4];
    const float* rb2       = (const float*)d_in[5];
    const float* gwi       = (const float*)d_in[6];
    const float* gwh       = (const float*)d_in[7];
    const float* gbi       = (const float*)d_in[8];
    const float* gbh       = (const float*)d_in[9];
    const float* hpw       = (const float*)d_in[10];
    const float* hpb       = (const float*)d_in[11];
    const float* ohw       = (const float*)d_in[12];
    const float* ohb       = (const float*)d_in[13];
    const float* vpw       = (const float*)d_in[14];
    const float* vpb       = (const float*)d_in[15];
    const float* vow       = (const float*)d_in[16];
    const float* vob       = (const float*)d_in[17];
    const float* opw       = (const float*)d_in[18];
    const float* opb       = (const float*)d_in[19];
    const float* tau       = (const float*)d_in[20];
    float* out = (float*)d_out;

    float* ws = (float*)d_ws;
    size_t off = 0;
    auto alloc = [&](size_t n) { float* p = ws + off; off += (n + 63) & ~(size_t)63; return p; };

    float* cb     = alloc(1024);
    float* h1     = alloc((size_t)MTOK * 1024);      // reused as v2 later
    float* logits = alloc((size_t)MTOK * 64);
    float* alpha  = alloc((size_t)MTOK * 64);
    float* slotin = alloc(256 * 64);
    float* part   = alloc((size_t)8 * 64 * 4 * 64);
    float* partw  = alloc(8 * 64 * 4);
    float* Snew   = alloc(256 * 64);
    float* v1c    = alloc((size_t)4096 * 4096);      // 4096-row chunk of v1
    float* v2     = h1;                               // h1 dead after logits

    // routing constant bias from slot_mean
    cb_kernel<<<8, 128, 0, stream>>>(slot_init, rw1, cb);
    // h1 = gelu(x @ rw1[:1024] + rb1 + cb)
    sgemm_k<1><<<dim3(1024 / 128, MTOK / 128), 256, 0, stream>>>(
        x, rw1, rb1, cb, h1, MTOK, 1024, 1024);
    // route logits
    logits_k<<<MTOK / 64, 256, 0, stream>>>(h1, rw2, rb2, tau, logits, MTOK, 1024);
    // top-32 + softmax -> dense alpha
    topk_k<<<MTOK / 4, 256, 0, stream>>>(logits, alpha);
    // slot pooling
    pool_part_k<<<dim3(64, 8), 256, 0, stream>>>(x, alpha, part, partw);
    pool_comb_k<<<64, 256, 0, stream>>>(part, partw, slotin);
    // GRU + slot MLP
    gru_k<<<256, 64, 0, stream>>>(slotin, slot_init, gwi, gwh, gbi, gbh,
                                  hpw, hpb, ohw, ohb, Snew);
    // broadcast to tokens; use d_out as out_b scratch (dead before final gemm)
    bcast_k<<<MTOK, 256, 0, stream>>>(alpha, Snew, out);
    // value MLP, chunked over 4096 rows to bound workspace
    for (int c = 0; c < 4; ++c) {
        const float* ob = out + (size_t)c * 4096 * 1024;
        sgemm_k<1><<<dim3(4096 / 128, 4096 / 128), 256, 0, stream>>>(
            ob, vpw, vpb, nullptr, v1c, 4096, 4096, 1024);
        sgemm_k<0><<<dim3(1024 / 128, 4096 / 128), 256, 0, stream>>>(
            v1c, vow, vob, nullptr, v2 + (size_t)c * 4096 * 1024, 4096, 1024, 4096);
    }
    // final projection
    sgemm_k<0><<<dim3(1024 / 128, MTOK / 128), 256, 0, stream>>>(
        v2, opw, opb, nullptr, out, MTOK, 1024, 1024);
    (void)in_sizes; (void)n_in; (void)out_size; (void)ws_size;
}

// Round 2
// 1409.354 us; speedup vs baseline: 3.8728x; 3.8728x over previous
//
#include <hip/hip_runtime.h>
#include <cstddef>
#include <cstdint>

// Problem constants
#define Bb 4
#define Tt 4096
#define Dd 1024
#define Hh 16
#define HDd 64
#define NSs 64
#define SPHh 4
#define HMm 4096
#define MTOK (Bb*Tt)   // 16384

typedef _Float16 f16x8 __attribute__((ext_vector_type(8)));
typedef float f32x4 __attribute__((ext_vector_type(4)));

__device__ __forceinline__ float gelu_f(float x) {
    return 0.5f * x * (1.0f + erff(x * 0.70710678118654752440f));
}

// ---------------- K0: cb[j] = sum_k slot_mean_full[k] * rw1[1024+k, j] ----------------
__global__ __launch_bounds__(128) void cb_kernel(const float* __restrict__ slot_init,
                                                 const float* __restrict__ rw1,
                                                 float* __restrict__ cb) {
    __shared__ float sm[64];
    int tid = threadIdx.x;
    if (tid < 64) {
        float s = 0.f;
        for (int i = 0; i < 64; ++i) s += slot_init[i * 64 + tid];
        sm[tid] = s * (1.0f / 64.0f);
    }
    __syncthreads();
    int j = blockIdx.x * 128 + tid;
    float acc = 0.f;
    for (int k = 0; k < 1024; ++k)
        acc = fmaf(sm[k & 63], rw1[(size_t)(1024 + k) * 1024 + j], acc);
    cb[j] = acc;
}

// ---------------- fp32 SGEMM (routing path only): C = gelu(A@B + bias + bias2) -------
template <int DO_GELU>
__global__ __launch_bounds__(256) void sgemm_k(const float* __restrict__ A,
                                               const float* __restrict__ Bw,
                                               const float* __restrict__ bias,
                                               const float* __restrict__ bias2,
                                               float* __restrict__ C,
                                               int M, int N, int K) {
    __shared__ float As[8][128];
    __shared__ float Bs[8][128];
    const int tid = threadIdx.x;
    const int brow = blockIdx.y * 128;
    const int bcol = blockIdx.x * 128;

    const int tx = (tid & 15) * 8;
    const int ty = (tid >> 4) * 8;

    const int arow = tid >> 1;
    const int acol = (tid & 1) * 4;
    const int brl  = tid >> 5;
    const int bcl  = (tid & 31) * 4;

    const float* Aptr = A + (size_t)(brow + arow) * K + acol;
    const float* Bptr = Bw + (size_t)brl * N + bcol + bcl;

    float acc[8][8] = {};

    for (int k0 = 0; k0 < K; k0 += 8) {
        float4 av = *(const float4*)(Aptr + k0);
        float4 bv = *(const float4*)(Bptr + (size_t)k0 * N);
        As[acol + 0][arow] = av.x;
        As[acol + 1][arow] = av.y;
        As[acol + 2][arow] = av.z;
        As[acol + 3][arow] = av.w;
        *(float4*)&Bs[brl][bcl] = bv;
        __syncthreads();
#pragma unroll
        for (int kk = 0; kk < 8; ++kk) {
            float a[8], b[8];
            *(float4*)&a[0] = *(const float4*)&As[kk][ty];
            *(float4*)&a[4] = *(const float4*)&As[kk][ty + 4];
            *(float4*)&b[0] = *(const float4*)&Bs[kk][tx];
            *(float4*)&b[4] = *(const float4*)&Bs[kk][tx + 4];
#pragma unroll
            for (int i = 0; i < 8; ++i)
#pragma unroll
                for (int j = 0; j < 8; ++j)
                    acc[i][j] = fmaf(a[i], b[j], acc[i][j]);
        }
        __syncthreads();
    }

#pragma unroll
    for (int i = 0; i < 8; ++i) {
        size_t row = (size_t)(brow + ty + i);
#pragma unroll
        for (int j = 0; j < 8; ++j) {
            int col = bcol + tx + j;
            float v = acc[i][j];
            if (bias)  v += bias[col];
            if (bias2) v += bias2[col];
            if (DO_GELU) v = gelu_f(v);
            C[row * N + col] = v;
        }
    }
}

// ---------------- K2: route logits, N=64 ----------------
__global__ __launch_bounds__(256) void logits_k(const float* __restrict__ A,
                                                const float* __restrict__ Bw,
                                                const float* __restrict__ rb2,
                                                const float* __restrict__ taup,
                                                float* __restrict__ Cl,
                                                int M, int K) {
    __shared__ float As[16][64];
    __shared__ float Bs[16][64];
    const int tid = threadIdx.x;
    const int m0 = blockIdx.x * 64;
    const int tx = (tid & 15) * 4;
    const int ty = (tid >> 4) * 4;
    const int arow = tid >> 2;
    const int acol = (tid & 3) * 4;
    const int brl = tid >> 4;
    const int bcl = (tid & 15) * 4;

    float acc[4][4] = {};

    for (int k0 = 0; k0 < K; k0 += 16) {
        float4 av = *(const float4*)(A + (size_t)(m0 + arow) * K + k0 + acol);
        float4 bv = *(const float4*)(Bw + (size_t)(k0 + brl) * 64 + bcl);
        As[acol + 0][arow] = av.x;
        As[acol + 1][arow] = av.y;
        As[acol + 2][arow] = av.z;
        As[acol + 3][arow] = av.w;
        *(float4*)&Bs[brl][bcl] = bv;
        __syncthreads();
#pragma unroll
        for (int kk = 0; kk < 16; ++kk) {
            float a[4], b[4];
            *(float4*)&a[0] = *(const float4*)&As[kk][ty];
            *(float4*)&b[0] = *(const float4*)&Bs[kk][tx];
#pragma unroll
            for (int i = 0; i < 4; ++i)
#pragma unroll
                for (int j = 0; j < 4; ++j)
                    acc[i][j] = fmaf(a[i], b[j], acc[i][j]);
        }
        __syncthreads();
    }
    float inv = 1.0f / (fabsf(taup[0]) + 0.1f);
#pragma unroll
    for (int i = 0; i < 4; ++i)
#pragma unroll
        for (int j = 0; j < 4; ++j)
            Cl[(size_t)(m0 + ty + i) * 64 + tx + j] = (acc[i][j] + rb2[tx + j]) * inv;
}

// ---------------- K3: top-32-of-64 + softmax -> dense alpha ----------------
__global__ __launch_bounds__(256) void topk_k(const float* __restrict__ logits,
                                              float* __restrict__ alpha) {
    int wave = threadIdx.x >> 6;
    int lane = threadIdx.x & 63;
    int t = blockIdx.x * 4 + wave;
    float li = logits[(size_t)t * 64 + lane];
    float m = li;
#pragma unroll
    for (int off = 32; off; off >>= 1) m = fmaxf(m, __shfl_xor(m, off, 64));
    int cnt = 0;
    for (int off = 1; off < 64; ++off) {
        int j = (lane + off) & 63;
        float lj = __shfl(li, j, 64);
        cnt += (lj > li) || (lj == li && j < lane);
    }
    float e = (cnt < 32) ? expf(li - m) : 0.0f;
    float s = e;
#pragma unroll
    for (int off = 32; off; off >>= 1) s += __shfl_xor(s, off, 64);
    alpha[(size_t)t * 64 + lane] = e / s;
}

// ---------------- K4: slot pooling (T-split partial sums) ----------------
__global__ __launch_bounds__(256) void pool_part_k(const float* __restrict__ x,
                                                   const float* __restrict__ alpha,
                                                   float* __restrict__ part,
                                                   float* __restrict__ partw) {
    int bh = blockIdx.x;
    int c = blockIdx.y;
    int b = bh >> 4, h = bh & 15;
    int tid = threadIdx.x;
    int s = tid >> 6, d = tid & 63;
    __shared__ float lx[16][64];
    __shared__ float la[16][4];
    float acc = 0.f, wacc = 0.f;
    const int tchunk = Tt / 8;
    const int t0base = c * tchunk;
    for (int t0 = 0; t0 < tchunk; t0 += 16) {
        int ttr = tid >> 4;
        int ddr = (tid & 15) * 4;
        size_t trow = (size_t)b * Tt + t0base + t0 + ttr;
        float4 xv = *(const float4*)(x + trow * Dd + h * 64 + ddr);
        *(float4*)&lx[ttr][ddr] = xv;
        if (tid < 64) {
            int tt2 = tid >> 2, ss = tid & 3;
            la[tt2][ss] = alpha[((size_t)b * Tt + t0base + t0 + tt2) * 64 + h * 4 + ss];
        }
        __syncthreads();
#pragma unroll
        for (int q = 0; q < 16; ++q) {
            float av = la[q][s];
            acc = fmaf(av, lx[q][d], acc);
            wacc += av;
        }
        __syncthreads();
    }
    part[(((size_t)c * 64 + bh) * 4 + s) * 64 + d] = acc;
    if (d == 0) partw[((size_t)c * 64 + bh) * 4 + s] = wacc;
}

__global__ __launch_bounds__(256) void pool_comb_k(const float* __restrict__ part,
                                                   const float* __restrict__ partw,
                                                   float* __restrict__ slot_in) {
    int bh = blockIdx.x;
    int tid = threadIdx.x;
    int s = tid >> 6, d = tid & 63;
    float acc = 0.f, w = 0.f;
    for (int c = 0; c < 8; ++c) {
        acc += part[(((size_t)c * 64 + bh) * 4 + s) * 64 + d];
        w   += partw[((size_t)c * 64 + bh) * 4 + s];
    }
    slot_in[((size_t)bh * 4 + s) * 64 + d] = acc / (w + 1e-8f);
}

// ---------------- K5: GRU + slot MLP, one wave per slot ----------------
__global__ __launch_bounds__(64) void gru_k(const float* __restrict__ slot_in,
                                            const float* __restrict__ slot_init,
                                            const float* __restrict__ gwi,
                                            const float* __restrict__ gwh,
                                            const float* __restrict__ gbi,
                                            const float* __restrict__ gbh,
                                            const float* __restrict__ hpw,
                                            const float* __restrict__ hpb,
                                            const float* __restrict__ ohw,
                                            const float* __restrict__ ohb,
                                            float* __restrict__ S_new) {
    int slot = blockIdx.x;
    int hs = slot & 63;
    int d = threadIdx.x;
    __shared__ float si[64], hp[64], hn[64], g[256];
    si[d] = slot_in[(size_t)slot * 64 + d];
    hp[d] = slot_init[(size_t)hs * 64 + d];
    __syncthreads();
    float gi_r = gbi[d], gi_z = gbi[64 + d], gi_n = gbi[128 + d];
    float gh_r = gbh[d], gh_z = gbh[64 + d], gh_n = gbh[128 + d];
    for (int k = 0; k < 64; ++k) {
        float sv = si[k], hv = hp[k];
        gi_r = fmaf(sv, gwi[(size_t)(d) * 64 + k], gi_r);
        gi_z = fmaf(sv, gwi[(size_t)(64 + d) * 64 + k], gi_z);
        gi_n = fmaf(sv, gwi[(size_t)(128 + d) * 64 + k], gi_n);
        gh_r = fmaf(hv, gwh[(size_t)(d) * 64 + k], gh_r);
        gh_z = fmaf(hv, gwh[(size_t)(64 + d) * 64 + k], gh_z);
        gh_n = fmaf(hv, gwh[(size_t)(128 + d) * 64 + k], gh_n);
    }
    float r = 1.0f / (1.0f + expf(-(gi_r + gh_r)));
    float z = 1.0f / (1.0f + expf(-(gi_z + gh_z)));
    float n = tanhf(gi_n + r * gh_n);
    float hnew = (1.0f - z) * n + z * hp[d];
    hn[d] = hnew;
    __syncthreads();
    float p0 = hpb[d], p1 = hpb[64 + d], p2 = hpb[128 + d], p3 = hpb[192 + d];
    for (int k = 0; k < 64; ++k) {
        float hv = hn[k];
        p0 = fmaf(hv, hpw[(size_t)k * 256 + d], p0);
        p1 = fmaf(hv, hpw[(size_t)k * 256 + 64 + d], p1);
        p2 = fmaf(hv, hpw[(size_t)k * 256 + 128 + d], p2);
        p3 = fmaf(hv, hpw[(size_t)k * 256 + 192 + d], p3);
    }
    g[d] = gelu_f(p0); g[64 + d] = gelu_f(p1); g[128 + d] = gelu_f(p2); g[192 + d] = gelu_f(p3);
    __syncthreads();
    float o = ohb[d];
    for (int j = 0; j < 256; ++j) o = fmaf(g[j], ohw[(size_t)j * 64 + d], o);
    S_new[(size_t)slot * 64 + d] = o;
}

// ---------------- K6: broadcast back to tokens (fp16 output) ----------------
__global__ __launch_bounds__(256) void bcast_k(const float* __restrict__ alpha,
                                               const float* __restrict__ S_new,
                                               _Float16* __restrict__ out_b) {
    int t = blockIdx.x;
    int b = t >> 12;
    __shared__ float a[64];
    int tid = threadIdx.x;
    if (tid < 64) a[tid] = alpha[(size_t)t * 64 + tid];
    __syncthreads();
#pragma unroll
    for (int o = tid; o < 1024; o += 256) {
        int h = o >> 6, d = o & 63;
        const float* sp = S_new + ((size_t)(b * 16 + h) * 4) * 64 + d;
        float acc = a[h * 4 + 0] * sp[0] + a[h * 4 + 1] * sp[64] +
                    a[h * 4 + 2] * sp[128] + a[h * 4 + 3] * sp[192];
        out_b[(size_t)t * 1024 + o] = (_Float16)acc;
    }
}

// ---------------- K7: transpose + fp32->fp16 convert: out[N,K] = (f16) in[K,N]^T -----
__global__ __launch_bounds__(256) void transp_f16_k(const float* __restrict__ in,
                                                    _Float16* __restrict__ out,
                                                    int K, int N) {
    __shared__ float t[32][33];
    int n0 = blockIdx.x * 32, k0 = blockIdx.y * 32;
    int tx = threadIdx.x & 31, ty = threadIdx.x >> 5;   // 32 x 8
#pragma unroll
    for (int i = 0; i < 32; i += 8)
        t[ty + i][tx] = in[(size_t)(k0 + ty + i) * N + n0 + tx];
    __syncthreads();
#pragma unroll
    for (int i = 0; i < 32; i += 8)
        out[(size_t)(n0 + ty + i) * K + k0 + tx] = (_Float16)t[tx][ty + i];
}

// ---------------- K8: fp16 MFMA GEMM: C = act(A[M,K] @ Bt[N,K]^T + bias) --------------
// 128x128 tile, BK=64, 4 waves, m97 structure (global_load_lds width 16, 2-barrier).
template <int DO_GELU, int OUT_F16>
__global__ __launch_bounds__(256) void hgemm_k(const _Float16* __restrict__ A,
                                               const _Float16* __restrict__ Bt,
                                               const float* __restrict__ bias,
                                               void* __restrict__ Cv,
                                               int M, int N, int K) {
    __shared__ __align__(16) _Float16 As[128][64];
    __shared__ __align__(16) _Float16 Bs[128][64];
    const int tid = threadIdx.x;
    const int wid = tid >> 6;
    const int lane = tid & 63;
    const int brow = blockIdx.y * 128;
    const int bcol = blockIdx.x * 128;
    const int wr = (wid >> 1) * 64;
    const int wc = (wid & 1) * 64;

    f32x4 acc[4][4];
#pragma unroll
    for (int m = 0; m < 4; ++m)
#pragma unroll
        for (int n = 0; n < 4; ++n)
            acc[m][n] = f32x4{0.f, 0.f, 0.f, 0.f};

    // staging geometry: per wave-issue, 64 lanes x 16B = 8 rows of 64 f16
    const int lrow = lane >> 3;          // 0..7
    const int lcol = (lane & 7) * 8;     // f16 elements

    const int fr = lane & 15;            // fragment row/col within 16
    const int fk = (lane >> 4) * 8;      // fragment k offset (contig 8)

    for (int k0 = 0; k0 < K; k0 += 64) {
#pragma unroll
        for (int i = 0; i < 4; ++i) {
            int seg = wid * 4 + i;       // 0..15, 8 rows each
            const _Float16* g = A + (size_t)(brow + seg * 8 + lrow) * K + k0 + lcol;
            __builtin_amdgcn_global_load_lds(
                (const __attribute__((address_space(1))) void*)g,
                (__attribute__((address_space(3))) void*)&As[seg * 8][0], 16, 0, 0);
        }
#pragma unroll
        for (int i = 0; i < 4; ++i) {
            int seg = wid * 4 + i;
            const _Float16* g = Bt + (size_t)(bcol + seg * 8 + lrow) * K + k0 + lcol;
            __builtin_amdgcn_global_load_lds(
                (const __attribute__((address_space(1))) void*)g,
                (__attribute__((address_space(3))) void*)&Bs[seg * 8][0], 16, 0, 0);
        }
        __syncthreads();
#pragma unroll
        for (int kb = 0; kb < 2; ++kb) {
            f16x8 af[4], bf[4];
#pragma unroll
            for (int m = 0; m < 4; ++m)
                af[m] = *(const f16x8*)&As[wr + m * 16 + fr][kb * 32 + fk];
#pragma unroll
            for (int n = 0; n < 4; ++n)
                bf[n] = *(const f16x8*)&Bs[wc + n * 16 + fr][kb * 32 + fk];
#pragma unroll
            for (int m = 0; m < 4; ++m)
#pragma unroll
                for (int n = 0; n < 4; ++n)
                    acc[m][n] = __builtin_amdgcn_mfma_f32_16x16x32_f16(af[m], bf[n], acc[m][n], 0, 0, 0);
        }
        __syncthreads();
    }

    // epilogue: C/D layout col=lane&15, row=(lane>>4)*4+reg  [m89/m91]
    const int crow = (lane >> 4) * 4;
#pragma unroll
    for (int m = 0; m < 4; ++m) {
        int row0 = brow + wr + m * 16 + crow;
#pragma unroll
        for (int n = 0; n < 4; ++n) {
            int col = bcol + wc + n * 16 + fr;
            float bv = bias ? bias[col] : 0.f;
#pragma unroll
            for (int r = 0; r < 4; ++r) {
                float v = acc[m][n][r] + bv;
                if (DO_GELU) v = gelu_f(v);
                size_t idx = (size_t)(row0 + r) * N + col;
                if (OUT_F16) ((_Float16*)Cv)[idx] = (_Float16)v;
                else ((float*)Cv)[idx] = v;
            }
        }
    }
}

extern "C" void kernel_launch(void* const* d_in, const int* in_sizes, int n_in,
                              void* d_out, int out_size, void* d_ws, size_t ws_size,
                              hipStream_t stream) {
    const float* x         = (const float*)d_in[0];
    const float* slot_init = (const float*)d_in[1];
    const float* rw1       = (const float*)d_in[2];
    const float* rb1       = (const float*)d_in[3];
    const float* rw2       = (const float*)d_in[4];
    const float* rb2       = (const float*)d_in[5];
    const float* gwi       = (const float*)d_in[6];
    const float* gwh       = (const float*)d_in[7];
    const float* gbi       = (const float*)d_in[8];
    const float* gbh       = (const float*)d_in[9];
    const float* hpw       = (const float*)d_in[10];
    const float* hpb       = (const float*)d_in[11];
    const float* ohw       = (const float*)d_in[12];
    const float* ohb       = (const float*)d_in[13];
    const float* vpw       = (const float*)d_in[14];
    const float* vpb       = (const float*)d_in[15];
    const float* vow       = (const float*)d_in[16];
    const float* vob       = (const float*)d_in[17];
    const float* opw       = (const float*)d_in[18];
    const float* opb       = (const float*)d_in[19];
    const float* tau       = (const float*)d_in[20];
    float* out = (float*)d_out;

    float* ws = (float*)d_ws;
    size_t off = 0;
    auto alloc = [&](size_t nfloats) { float* p = ws + off; off += (nfloats + 63) & ~(size_t)63; return p; };

    float* cb     = alloc(1024);
    float* h1     = alloc((size_t)MTOK * 1024);       // fp32; reused after topk:
    _Float16* outb = (_Float16*)h1;                    //   first 32MB: out_b fp16
    _Float16* v2   = (_Float16*)h1 + (size_t)MTOK * 1024; // second 32MB: v2 fp16
    float* logits = alloc((size_t)MTOK * 64);
    float* alpha  = alloc((size_t)MTOK * 64);
    float* slotin = alloc(256 * 64);
    float* part   = alloc((size_t)8 * 64 * 4 * 64);
    float* partw  = alloc(8 * 64 * 4);
    float* Snew   = alloc(256 * 64);
    _Float16* vpwT = (_Float16*)alloc((size_t)HMm * Dd / 2);   // [4096,1024] f16
    _Float16* vowT = (_Float16*)alloc((size_t)Dd * HMm / 2);   // [1024,4096] f16
    _Float16* opwT = (_Float16*)alloc((size_t)Dd * Dd / 2);    // [1024,1024] f16
    _Float16* v1c  = (_Float16*)alloc((size_t)4096 * HMm / 2); // [4096,4096] f16 chunk

    // ---- routing (fp32) ----
    cb_kernel<<<8, 128, 0, stream>>>(slot_init, rw1, cb);
    sgemm_k<1><<<dim3(1024 / 128, MTOK / 128), 256, 0, stream>>>(
        x, rw1, rb1, cb, h1, MTOK, 1024, 1024);
    logits_k<<<MTOK / 64, 256, 0, stream>>>(h1, rw2, rb2, tau, logits, MTOK, 1024);
    topk_k<<<MTOK / 4, 256, 0, stream>>>(logits, alpha);

    // ---- weight transposes (independent; fp32 -> fp16 [N,K]) ----
    transp_f16_k<<<dim3(HMm / 32, Dd / 32), 256, 0, stream>>>(vpw, vpwT, Dd, HMm);
    transp_f16_k<<<dim3(Dd / 32, HMm / 32), 256, 0, stream>>>(vow, vowT, HMm, Dd);
    transp_f16_k<<<dim3(Dd / 32, Dd / 32), 256, 0, stream>>>(opw, opwT, Dd, Dd);

    // ---- slot pooling + GRU + slot MLP ----
    pool_part_k<<<dim3(64, 8), 256, 0, stream>>>(x, alpha, part, partw);
    pool_comb_k<<<64, 256, 0, stream>>>(part, partw, slotin);
    gru_k<<<256, 64, 0, stream>>>(slotin, slot_init, gwi, gwh, gbi, gbh,
                                  hpw, hpb, ohw, ohb, Snew);

    // ---- broadcast to tokens (fp16 out_b; h1 fp32 is dead now) ----
    bcast_k<<<MTOK, 256, 0, stream>>>(alpha, Snew, outb);

    // ---- value MLP on MFMA, chunked over 4096 rows ----
    for (int c = 0; c < 4; ++c) {
        const _Float16* ob = outb + (size_t)c * 4096 * Dd;
        hgemm_k<1, 1><<<dim3(HMm / 128, 4096 / 128), 256, 0, stream>>>(
            ob, vpwT, vpb, v1c, 4096, HMm, Dd);
        hgemm_k<0, 1><<<dim3(Dd / 128, 4096 / 128), 256, 0, stream>>>(
            v1c, vowT, vob, v2 + (size_t)c * 4096 * Dd, 4096, Dd, HMm);
    }
    // ---- final projection (fp32 out) ----
    hgemm_k<0, 0><<<dim3(Dd / 128, MTOK / 128), 256, 0, stream>>>(
        v2, opwT, opb, out, MTOK, Dd, Dd);

    (void)in_sizes; (void)n_in; (void)out_size; (void)ws_size;
}

// Round 3
// 1146.730 us; speedup vs baseline: 4.7597x; 1.2290x over previous
//
#include <hip/hip_runtime.h>
#include <cstddef>
#include <cstdint>

// Problem constants
#define Bb 4
#define Tt 4096
#define Dd 1024
#define Hh 16
#define HDd 64
#define NSs 64
#define SPHh 4
#define HMm 4096
#define MTOK (Bb*Tt)   // 16384

typedef _Float16 f16x8 __attribute__((ext_vector_type(8)));
typedef float f32x4 __attribute__((ext_vector_type(4)));

__device__ __forceinline__ float gelu_f(float x) {
    return 0.5f * x * (1.0f + erff(x * 0.70710678118654752440f));
}

// ---------------- K0: cb[j] = sum_k slot_mean_full[k] * rw1[1024+k, j] ----------------
__global__ __launch_bounds__(128) void cb_kernel(const float* __restrict__ slot_init,
                                                 const float* __restrict__ rw1,
                                                 float* __restrict__ cb) {
    __shared__ float sm[64];
    int tid = threadIdx.x;
    if (tid < 64) {
        float s = 0.f;
        for (int i = 0; i < 64; ++i) s += slot_init[i * 64 + tid];
        sm[tid] = s * (1.0f / 64.0f);
    }
    __syncthreads();
    int j = blockIdx.x * 128 + tid;
    float acc = 0.f;
    for (int k = 0; k < 1024; ++k)
        acc = fmaf(sm[k & 63], rw1[(size_t)(1024 + k) * 1024 + j], acc);
    cb[j] = acc;
}

// ---------------- fp32 SGEMM (routing h1): BK=16, register-prefetch double buffer ----
// Per-thread k-accumulation order identical to BK=8 version -> bit-identical logits.
template <int DO_GELU>
__global__ __launch_bounds__(256) void sgemm16_k(const float* __restrict__ A,
                                                 const float* __restrict__ Bw,
                                                 const float* __restrict__ bias,
                                                 const float* __restrict__ bias2,
                                                 float* __restrict__ C,
                                                 int M, int N, int K) {
    __shared__ float As[16][128];
    __shared__ float Bs[16][128];
    const int tid = threadIdx.x;
    const int brow = blockIdx.y * 128;
    const int bcol = blockIdx.x * 128;

    const int tx = (tid & 15) * 8;
    const int ty = (tid >> 4) * 8;

    const int arow = tid >> 1;           // 0..127
    const int acol = (tid & 1) * 8;      // 0 or 8
    const int brl  = tid >> 4;           // 0..15
    const int bcl  = (tid & 15) * 8;     // 0..120

    const float* Ap = A + (size_t)(brow + arow) * K + acol;
    const float* Bp = Bw + (size_t)brl * N + bcol + bcl;

    float4 a0 = *(const float4*)(Ap);
    float4 a1 = *(const float4*)(Ap + 4);
    float4 b0 = *(const float4*)(Bp);
    float4 b1 = *(const float4*)(Bp + 4);

    float acc[8][8] = {};

    for (int k0 = 0; k0 < K; k0 += 16) {
        As[acol + 0][arow] = a0.x; As[acol + 1][arow] = a0.y;
        As[acol + 2][arow] = a0.z; As[acol + 3][arow] = a0.w;
        As[acol + 4][arow] = a1.x; As[acol + 5][arow] = a1.y;
        As[acol + 6][arow] = a1.z; As[acol + 7][arow] = a1.w;
        *(float4*)&Bs[brl][bcl] = b0;
        *(float4*)&Bs[brl][bcl + 4] = b1;
        __syncthreads();
        if (k0 + 16 < K) {
            a0 = *(const float4*)(Ap + k0 + 16);
            a1 = *(const float4*)(Ap + k0 + 20);
            b0 = *(const float4*)(Bp + (size_t)(k0 + 16) * N);
            b1 = *(const float4*)(Bp + (size_t)(k0 + 16) * N + 4);
        }
#pragma unroll
        for (int kk = 0; kk < 16; ++kk) {
            float a[8], b[8];
            *(float4*)&a[0] = *(const float4*)&As[kk][ty];
            *(float4*)&a[4] = *(const float4*)&As[kk][ty + 4];
            *(float4*)&b[0] = *(const float4*)&Bs[kk][tx];
            *(float4*)&b[4] = *(const float4*)&Bs[kk][tx + 4];
#pragma unroll
            for (int i = 0; i < 8; ++i)
#pragma unroll
                for (int j = 0; j < 8; ++j)
                    acc[i][j] = fmaf(a[i], b[j], acc[i][j]);
        }
        __syncthreads();
    }

#pragma unroll
    for (int i = 0; i < 8; ++i) {
        size_t row = (size_t)(brow + ty + i);
#pragma unroll
        for (int j = 0; j < 8; ++j) {
            int col = bcol + tx + j;
            float v = acc[i][j];
            if (bias)  v += bias[col];
            if (bias2) v += bias2[col];
            if (DO_GELU) v = gelu_f(v);
            C[row * N + col] = v;
        }
    }
}

// ---------------- K2: route logits, N=64 ----------------
__global__ __launch_bounds__(256) void logits_k(const float* __restrict__ A,
                                                const float* __restrict__ Bw,
                                                const float* __restrict__ rb2,
                                                const float* __restrict__ taup,
                                                float* __restrict__ Cl,
                                                int M, int K) {
    __shared__ float As[16][64];
    __shared__ float Bs[16][64];
    const int tid = threadIdx.x;
    const int m0 = blockIdx.x * 64;
    const int tx = (tid & 15) * 4;
    const int ty = (tid >> 4) * 4;
    const int arow = tid >> 2;
    const int acol = (tid & 3) * 4;
    const int brl = tid >> 4;
    const int bcl = (tid & 15) * 4;

    float acc[4][4] = {};

    for (int k0 = 0; k0 < K; k0 += 16) {
        float4 av = *(const float4*)(A + (size_t)(m0 + arow) * K + k0 + acol);
        float4 bv = *(const float4*)(Bw + (size_t)(k0 + brl) * 64 + bcl);
        As[acol + 0][arow] = av.x;
        As[acol + 1][arow] = av.y;
        As[acol + 2][arow] = av.z;
        As[acol + 3][arow] = av.w;
        *(float4*)&Bs[brl][bcl] = bv;
        __syncthreads();
#pragma unroll
        for (int kk = 0; kk < 16; ++kk) {
            float a[4], b[4];
            *(float4*)&a[0] = *(const float4*)&As[kk][ty];
            *(float4*)&b[0] = *(const float4*)&Bs[kk][tx];
#pragma unroll
            for (int i = 0; i < 4; ++i)
#pragma unroll
                for (int j = 0; j < 4; ++j)
                    acc[i][j] = fmaf(a[i], b[j], acc[i][j]);
        }
        __syncthreads();
    }
    float inv = 1.0f / (fabsf(taup[0]) + 0.1f);
#pragma unroll
    for (int i = 0; i < 4; ++i)
#pragma unroll
        for (int j = 0; j < 4; ++j)
            Cl[(size_t)(m0 + ty + i) * 64 + tx + j] = (acc[i][j] + rb2[tx + j]) * inv;
}

// ---------------- K3: top-32-of-64 + softmax -> dense alpha (fp32 + f16 copy) --------
__global__ __launch_bounds__(256) void topk_k(const float* __restrict__ logits,
                                              float* __restrict__ alpha,
                                              _Float16* __restrict__ alpha16) {
    int wave = threadIdx.x >> 6;
    int lane = threadIdx.x & 63;
    int t = blockIdx.x * 4 + wave;
    float li = logits[(size_t)t * 64 + lane];
    float m = li;
#pragma unroll
    for (int off = 32; off; off >>= 1) m = fmaxf(m, __shfl_xor(m, off, 64));
    int cnt = 0;
    for (int off = 1; off < 64; ++off) {
        int j = (lane + off) & 63;
        float lj = __shfl(li, j, 64);
        cnt += (lj > li) || (lj == li && j < lane);
    }
    float e = (cnt < 32) ? expf(li - m) : 0.0f;
    float s = e;
#pragma unroll
    for (int off = 32; off; off >>= 1) s += __shfl_xor(s, off, 64);
    float a = e / s;
    alpha[(size_t)t * 64 + lane] = a;
    alpha16[(size_t)t * 64 + lane] = (_Float16)a;
}

// ---------------- K4: slot pooling (T-split partial sums) ----------------
__global__ __launch_bounds__(256) void pool_part_k(const float* __restrict__ x,
                                                   const float* __restrict__ alpha,
                                                   float* __restrict__ part,
                                                   float* __restrict__ partw) {
    int bh = blockIdx.x;
    int c = blockIdx.y;
    int b = bh >> 4, h = bh & 15;
    int tid = threadIdx.x;
    int s = tid >> 6, d = tid & 63;
    __shared__ float lx[16][64];
    __shared__ float la[16][4];
    float acc = 0.f, wacc = 0.f;
    const int tchunk = Tt / 8;
    const int t0base = c * tchunk;
    for (int t0 = 0; t0 < tchunk; t0 += 16) {
        int ttr = tid >> 4;
        int ddr = (tid & 15) * 4;
        size_t trow = (size_t)b * Tt + t0base + t0 + ttr;
        float4 xv = *(const float4*)(x + trow * Dd + h * 64 + ddr);
        *(float4*)&lx[ttr][ddr] = xv;
        if (tid < 64) {
            int tt2 = tid >> 2, ss = tid & 3;
            la[tt2][ss] = alpha[((size_t)b * Tt + t0base + t0 + tt2) * 64 + h * 4 + ss];
        }
        __syncthreads();
#pragma unroll
        for (int q = 0; q < 16; ++q) {
            float av = la[q][s];
            acc = fmaf(av, lx[q][d], acc);
            wacc += av;
        }
        __syncthreads();
    }
    part[(((size_t)c * 64 + bh) * 4 + s) * 64 + d] = acc;
    if (d == 0) partw[((size_t)c * 64 + bh) * 4 + s] = wacc;
}

__global__ __launch_bounds__(256) void pool_comb_k(const float* __restrict__ part,
                                                   const float* __restrict__ partw,
                                                   float* __restrict__ slot_in) {
    int bh = blockIdx.x;
    int tid = threadIdx.x;
    int s = tid >> 6, d = tid & 63;
    float acc = 0.f, w = 0.f;
    for (int c = 0; c < 8; ++c) {
        acc += part[(((size_t)c * 64 + bh) * 4 + s) * 64 + d];
        w   += partw[((size_t)c * 64 + bh) * 4 + s];
    }
    slot_in[((size_t)bh * 4 + s) * 64 + d] = acc / (w + 1e-8f);
}

// ---------------- K5: GRU + slot MLP, one wave per slot ----------------
__global__ __launch_bounds__(64) void gru_k(const float* __restrict__ slot_in,
                                            const float* __restrict__ slot_init,
                                            const float* __restrict__ gwi,
                                            const float* __restrict__ gwh,
                                            const float* __restrict__ gbi,
                                            const float* __restrict__ gbh,
                                            const float* __restrict__ hpw,
                                            const float* __restrict__ hpb,
                                            const float* __restrict__ ohw,
                                            const float* __restrict__ ohb,
                                            float* __restrict__ S_new) {
    int slot = blockIdx.x;
    int hs = slot & 63;
    int d = threadIdx.x;
    __shared__ float si[64], hp[64], hn[64], g[256];
    si[d] = slot_in[(size_t)slot * 64 + d];
    hp[d] = slot_init[(size_t)hs * 64 + d];
    __syncthreads();
    float gi_r = gbi[d], gi_z = gbi[64 + d], gi_n = gbi[128 + d];
    float gh_r = gbh[d], gh_z = gbh[64 + d], gh_n = gbh[128 + d];
    for (int k = 0; k < 64; ++k) {
        float sv = si[k], hv = hp[k];
        gi_r = fmaf(sv, gwi[(size_t)(d) * 64 + k], gi_r);
        gi_z = fmaf(sv, gwi[(size_t)(64 + d) * 64 + k], gi_z);
        gi_n = fmaf(sv, gwi[(size_t)(128 + d) * 64 + k], gi_n);
        gh_r = fmaf(hv, gwh[(size_t)(d) * 64 + k], gh_r);
        gh_z = fmaf(hv, gwh[(size_t)(64 + d) * 64 + k], gh_z);
        gh_n = fmaf(hv, gwh[(size_t)(128 + d) * 64 + k], gh_n);
    }
    float r = 1.0f / (1.0f + expf(-(gi_r + gh_r)));
    float z = 1.0f / (1.0f + expf(-(gi_z + gh_z)));
    float n = tanhf(gi_n + r * gh_n);
    float hnew = (1.0f - z) * n + z * hp[d];
    hn[d] = hnew;
    __syncthreads();
    float p0 = hpb[d], p1 = hpb[64 + d], p2 = hpb[128 + d], p3 = hpb[192 + d];
    for (int k = 0; k < 64; ++k) {
        float hv = hn[k];
        p0 = fmaf(hv, hpw[(size_t)k * 256 + d], p0);
        p1 = fmaf(hv, hpw[(size_t)k * 256 + 64 + d], p1);
        p2 = fmaf(hv, hpw[(size_t)k * 256 + 128 + d], p2);
        p3 = fmaf(hv, hpw[(size_t)k * 256 + 192 + d], p3);
    }
    g[d] = gelu_f(p0); g[64 + d] = gelu_f(p1); g[128 + d] = gelu_f(p2); g[192 + d] = gelu_f(p3);
    __syncthreads();
    float o = ohb[d];
    for (int j = 0; j < 256; ++j) o = fmaf(g[j], ohw[(size_t)j * 64 + d], o);
    S_new[(size_t)slot * 64 + d] = o;
}

// ---------------- K6: P^T[b][j][hs] = sum_d S_new[b,hs,d] * vpw[h*64+d, j]  (f16) ----
__global__ __launch_bounds__(256) void pmat_k(const float* __restrict__ Snew,
                                              const float* __restrict__ vpw,
                                              _Float16* __restrict__ PT) {
    int tid = threadIdx.x;
    int j = blockIdx.x * 64 + (tid & 63);
    int bq = tid >> 6;                       // batch 0..3 (one per wave)
    for (int hb = 0; hb < 8; ++hb) {
        float acc[8] = {};
        int h0 = hb * 2;
        for (int d = 0; d < 64; ++d) {
            float w0 = vpw[(size_t)(h0 * 64 + d) * HMm + j];
            float w1 = vpw[(size_t)((h0 + 1) * 64 + d) * HMm + j];
#pragma unroll
            for (int s = 0; s < 4; ++s) {
                acc[s]     = fmaf(Snew[((size_t)bq * 64 + h0 * 4 + s) * 64 + d], w0, acc[s]);
                acc[4 + s] = fmaf(Snew[((size_t)bq * 64 + (h0 + 1) * 4 + s) * 64 + d], w1, acc[4 + s]);
            }
        }
        f16x8 o;
#pragma unroll
        for (int i = 0; i < 8; ++i) o[i] = (_Float16)acc[i];
        *(f16x8*)&PT[((size_t)bq * 4096 + j) * 64 + hb * 8] = o;
    }
}

// ---------------- K7: transpose + fp32->fp16 convert: out[N,K] = (f16) in[K,N]^T -----
__global__ __launch_bounds__(256) void transp_f16_k(const float* __restrict__ in,
                                                    _Float16* __restrict__ out,
                                                    int K, int N) {
    __shared__ float t[32][33];
    int n0 = blockIdx.x * 32, k0 = blockIdx.y * 32;
    int tx = threadIdx.x & 31, ty = threadIdx.x >> 5;   // 32 x 8
#pragma unroll
    for (int i = 0; i < 32; i += 8)
        t[ty + i][tx] = in[(size_t)(k0 + ty + i) * N + n0 + tx];
    __syncthreads();
#pragma unroll
    for (int i = 0; i < 32; i += 8)
        out[(size_t)(n0 + ty + i) * K + k0 + tx] = (_Float16)t[tx][ty + i];
}

// ---------------- K8: fp16 MFMA GEMM: C = act(A[M,K] @ Bt[N,K]^T + bias) --------------
// 128x128 tile, BK=64, 4 waves, m97 structure (global_load_lds width 16, 2-barrier).
template <int DO_GELU, int OUT_F16>
__global__ __launch_bounds__(256) void hgemm_k(const _Float16* __restrict__ A,
                                               const _Float16* __restrict__ Bt,
                                               const float* __restrict__ bias,
                                               void* __restrict__ Cv,
                                               int M, int N, int K) {
    __shared__ __align__(16) _Float16 As[128][64];
    __shared__ __align__(16) _Float16 Bs[128][64];
    const int tid = threadIdx.x;
    const int wid = tid >> 6;
    const int lane = tid & 63;
    const int brow = blockIdx.y * 128;
    const int bcol = blockIdx.x * 128;
    const int wr = (wid >> 1) * 64;
    const int wc = (wid & 1) * 64;

    f32x4 acc[4][4];
#pragma unroll
    for (int m = 0; m < 4; ++m)
#pragma unroll
        for (int n = 0; n < 4; ++n)
            acc[m][n] = f32x4{0.f, 0.f, 0.f, 0.f};

    const int lrow = lane >> 3;          // 0..7
    const int lcol = (lane & 7) * 8;     // f16 elements

    const int fr = lane & 15;
    const int fk = (lane >> 4) * 8;

    for (int k0 = 0; k0 < K; k0 += 64) {
#pragma unroll
        for (int i = 0; i < 4; ++i) {
            int seg = wid * 4 + i;
            const _Float16* g = A + (size_t)(brow + seg * 8 + lrow) * K + k0 + lcol;
            __builtin_amdgcn_global_load_lds(
                (const __attribute__((address_space(1))) void*)g,
                (__attribute__((address_space(3))) void*)&As[seg * 8][0], 16, 0, 0);
        }
#pragma unroll
        for (int i = 0; i < 4; ++i) {
            int seg = wid * 4 + i;
            const _Float16* g = Bt + (size_t)(bcol + seg * 8 + lrow) * K + k0 + lcol;
            __builtin_amdgcn_global_load_lds(
                (const __attribute__((address_space(1))) void*)g,
                (__attribute__((address_space(3))) void*)&Bs[seg * 8][0], 16, 0, 0);
        }
        __syncthreads();
#pragma unroll
        for (int kb = 0; kb < 2; ++kb) {
            f16x8 af[4], bf[4];
#pragma unroll
            for (int m = 0; m < 4; ++m)
                af[m] = *(const f16x8*)&As[wr + m * 16 + fr][kb * 32 + fk];
#pragma unroll
            for (int n = 0; n < 4; ++n)
                bf[n] = *(const f16x8*)&Bs[wc + n * 16 + fr][kb * 32 + fk];
#pragma unroll
            for (int m = 0; m < 4; ++m)
#pragma unroll
                for (int n = 0; n < 4; ++n)
                    acc[m][n] = __builtin_amdgcn_mfma_f32_16x16x32_f16(af[m], bf[n], acc[m][n], 0, 0, 0);
        }
        __syncthreads();
    }

    const int crow = (lane >> 4) * 4;
#pragma unroll
    for (int m = 0; m < 4; ++m) {
        int row0 = brow + wr + m * 16 + crow;
#pragma unroll
        for (int n = 0; n < 4; ++n) {
            int col = bcol + wc + n * 16 + fr;
            float bv = bias ? bias[col] : 0.f;
#pragma unroll
            for (int r = 0; r < 4; ++r) {
                float v = acc[m][n][r] + bv;
                if (DO_GELU) v = gelu_f(v);
                size_t idx = (size_t)(row0 + r) * N + col;
                if (OUT_F16) ((_Float16*)Cv)[idx] = (_Float16)v;
                else ((float*)Cv)[idx] = v;
            }
        }
    }
}

extern "C" void kernel_launch(void* const* d_in, const int* in_sizes, int n_in,
                              void* d_out, int out_size, void* d_ws, size_t ws_size,
                              hipStream_t stream) {
    const float* x         = (const float*)d_in[0];
    const float* slot_init = (const float*)d_in[1];
    const float* rw1       = (const float*)d_in[2];
    const float* rb1       = (const float*)d_in[3];
    const float* rw2       = (const float*)d_in[4];
    const float* rb2       = (const float*)d_in[5];
    const float* gwi       = (const float*)d_in[6];
    const float* gwh       = (const float*)d_in[7];
    const float* gbi       = (const float*)d_in[8];
    const float* gbh       = (const float*)d_in[9];
    const float* hpw       = (const float*)d_in[10];
    const float* hpb       = (const float*)d_in[11];
    const float* ohw       = (const float*)d_in[12];
    const float* ohb       = (const float*)d_in[13];
    const float* vpw       = (const float*)d_in[14];
    const float* vpb       = (const float*)d_in[15];
    const float* vow       = (const float*)d_in[16];
    const float* vob       = (const float*)d_in[17];
    const float* opw       = (const float*)d_in[18];
    const float* opb       = (const float*)d_in[19];
    const float* tau       = (const float*)d_in[20];
    float* out = (float*)d_out;

    float* ws = (float*)d_ws;
    size_t off = 0;
    auto alloc = [&](size_t nfloats) { float* p = ws + off; off += (nfloats + 63) & ~(size_t)63; return p; };

    float* cb     = alloc(1024);
    float* h1     = alloc((size_t)MTOK * 1024);            // fp32; dead after logits:
    _Float16* v1cc = (_Float16*)h1;                         //   reused as v1 row-chunk [8192,4096] f16
    float* logits = alloc((size_t)MTOK * 64);
    float* alpha  = alloc((size_t)MTOK * 64);
    _Float16* alpha16 = (_Float16*)alloc((size_t)MTOK * 64 / 2);
    float* slotin = alloc(256 * 64);
    float* part   = alloc((size_t)8 * 64 * 4 * 64);
    float* partw  = alloc(8 * 64 * 4);
    float* Snew   = alloc(256 * 64);
    _Float16* PT   = (_Float16*)alloc((size_t)Bb * HMm * 64 / 2);  // [4,4096,64] f16
    _Float16* vowT = (_Float16*)alloc((size_t)Dd * HMm / 2);       // [1024,4096] f16
    _Float16* opwT = (_Float16*)alloc((size_t)Dd * Dd / 2);        // [1024,1024] f16
    _Float16* v2f16 = (_Float16*)alloc((size_t)MTOK * Dd / 2);     // [16384,1024] f16

    // ---- routing (fp32) ----
    cb_kernel<<<8, 128, 0, stream>>>(slot_init, rw1, cb);
    sgemm16_k<1><<<dim3(1024 / 128, MTOK / 128), 256, 0, stream>>>(
        x, rw1, rb1, cb, h1, MTOK, 1024, 1024);
    logits_k<<<MTOK / 64, 256, 0, stream>>>(h1, rw2, rb2, tau, logits, MTOK, 1024);
    topk_k<<<MTOK / 4, 256, 0, stream>>>(logits, alpha, alpha16);

    // ---- weight transposes (fp32 -> fp16 [N,K]) ----
    transp_f16_k<<<dim3(Dd / 32, HMm / 32), 256, 0, stream>>>(vow, vowT, HMm, Dd);
    transp_f16_k<<<dim3(Dd / 32, Dd / 32), 256, 0, stream>>>(opw, opwT, Dd, Dd);

    // ---- slot pooling + GRU + slot MLP ----
    pool_part_k<<<dim3(64, 8), 256, 0, stream>>>(x, alpha, part, partw);
    pool_comb_k<<<64, 256, 0, stream>>>(part, partw, slotin);
    gru_k<<<256, 64, 0, stream>>>(slotin, slot_init, gwi, gwh, gbi, gbh,
                                  hpw, hpb, ohw, ohb, Snew);

    // ---- P^T[b] = (S_emb[b] @ vpw)^T : rank-64 structure kills GEMM1 ----
    pmat_k<<<HMm / 64, 256, 0, stream>>>(Snew, vpw, PT);

    // ---- value MLP: v1 = gelu(alpha @ P[b] + vpb) via K=64 MFMA GEMM, then GEMM2 ----
    for (int c = 0; c < 2; ++c) {
        for (int q = 0; q < 2; ++q) {
            int b = c * 2 + q;
            hgemm_k<1, 1><<<dim3(HMm / 128, Tt / 128), 256, 0, stream>>>(
                alpha16 + (size_t)b * Tt * 64, PT + (size_t)b * HMm * 64, vpb,
                v1cc + (size_t)q * Tt * HMm, Tt, HMm, 64);
        }
        hgemm_k<0, 1><<<dim3(Dd / 128, 8192 / 128), 256, 0, stream>>>(
            v1cc, vowT, vob, v2f16 + (size_t)c * 8192 * Dd, 8192, Dd, HMm);
    }
    // ---- final projection (fp32 out) ----
    hgemm_k<0, 0><<<dim3(Dd / 128, MTOK / 128), 256, 0, stream>>>(
        v2f16, opwT, opb, out, MTOK, Dd, Dd);

    (void)in_sizes; (void)n_in; (void)out_size; (void)ws_size;
}

// Round 4
// 850.229 us; speedup vs baseline: 6.4196x; 1.3487x over previous
//
#include <hip/hip_runtime.h>
#include <cstddef>
#include <cstdint>

// Problem constants
#define Bb 4
#define Tt 4096
#define Dd 1024
#define Hh 16
#define HDd 64
#define NSs 64
#define SPHh 4
#define HMm 4096
#define MTOK (Bb*Tt)   // 16384

typedef _Float16 f16x8 __attribute__((ext_vector_type(8)));
typedef float f32x4 __attribute__((ext_vector_type(4)));

__device__ __forceinline__ float gelu_f(float x) {
    return 0.5f * x * (1.0f + erff(x * 0.70710678118654752440f));
}

// ---------------- K0: cb[j] = sum_k slot_mean_full[k] * rw1[1024+k, j] ----------------
__global__ __launch_bounds__(128) void cb_kernel(const float* __restrict__ slot_init,
                                                 const float* __restrict__ rw1,
                                                 float* __restrict__ cb) {
    __shared__ float sm[64];
    int tid = threadIdx.x;
    if (tid < 64) {
        float s = 0.f;
        for (int i = 0; i < 64; ++i) s += slot_init[i * 64 + tid];
        sm[tid] = s * (1.0f / 64.0f);
    }
    __syncthreads();
    int j = blockIdx.x * 128 + tid;
    float acc = 0.f;
    for (int k = 0; k < 1024; ++k)
        acc = fmaf(sm[k & 63], rw1[(size_t)(1024 + k) * 1024 + j], acc);
    cb[j] = acc;
}

// ---------------- K1: rw1[:1024] -> transposed split-f16 planes [N=1024][K=1024] ------
__global__ __launch_bounds__(256) void wsplitT_k(const float* __restrict__ rw1,
                                                 _Float16* __restrict__ whiT,
                                                 _Float16* __restrict__ wloT) {
    __shared__ float t[32][33];
    int n0 = blockIdx.x * 32, k0 = blockIdx.y * 32;
    int tx = threadIdx.x & 31, ty = threadIdx.x >> 5;   // 32 x 8
#pragma unroll
    for (int i = 0; i < 32; i += 8)
        t[ty + i][tx] = rw1[(size_t)(k0 + ty + i) * 1024 + n0 + tx];
    __syncthreads();
#pragma unroll
    for (int i = 0; i < 32; i += 8) {
        float v = t[tx][ty + i];
        _Float16 h = (_Float16)v;
        _Float16 l = (_Float16)(v - (float)h);
        whiT[(size_t)(n0 + ty + i) * 1024 + k0 + tx] = h;
        wloT[(size_t)(n0 + ty + i) * 1024 + k0 + tx] = l;
    }
}

// ---------------- K1b: split-fp16 MFMA routing GEMM --------------------------------
// C[M,N] fp32 = gelu(A[M,K]fp32 @ (Bhi+Blo)[N,K]^T + bias1 + bias2), 3-term Markidis.
// 128x128 tile, BK=32, A reg-staged with on-the-fly split (padded LDS), B via gload_lds.
__global__ __launch_bounds__(256) void hgemm3_k(const float* __restrict__ A,
                                                const _Float16* __restrict__ Bh,
                                                const _Float16* __restrict__ Bl,
                                                const float* __restrict__ bias1,
                                                const float* __restrict__ bias2,
                                                float* __restrict__ C,
                                                int M, int N, int K) {
    __shared__ __align__(16) _Float16 Ahs[128][48];   // +16 pad -> 96B row stride
    __shared__ __align__(16) _Float16 Als[128][48];
    __shared__ __align__(16) _Float16 Bhs[128][32];   // linear (gload_lds dest)
    __shared__ __align__(16) _Float16 Bls[128][32];
    const int tid = threadIdx.x;
    const int wid = tid >> 6;
    const int lane = tid & 63;
    const int brow = blockIdx.y * 128;
    const int bcol = blockIdx.x * 128;
    const int wr = (wid >> 1) * 64;
    const int wc = (wid & 1) * 64;

    // A staging: each lane loads 16 floats of one row-half
    const int ra = wid * 32 + (lane >> 1);   // block-local row 0..127
    const int pa = (lane & 1) * 16;          // float col offset 0/16
    const float* Ap = A + (size_t)(brow + ra) * K + pa;

    // B staging (gload_lds lane image: 16 rows x 32 f16 per issue)
    const int rb = lane >> 2;
    const int cbk = (lane & 3) * 8;

    const int fr = lane & 15;
    const int fk = (lane >> 4) * 8;
    const int crow = (lane >> 4) * 4;

    f32x4 acc[4][4];
#pragma unroll
    for (int m = 0; m < 4; ++m)
#pragma unroll
        for (int n = 0; n < 4; ++n)
            acc[m][n] = f32x4{0.f, 0.f, 0.f, 0.f};

    for (int k0 = 0; k0 < K; k0 += 32) {
        float av[16];
        *(float4*)&av[0]  = *(const float4*)(Ap + k0);
        *(float4*)&av[4]  = *(const float4*)(Ap + k0 + 4);
        *(float4*)&av[8]  = *(const float4*)(Ap + k0 + 8);
        *(float4*)&av[12] = *(const float4*)(Ap + k0 + 12);
        f16x8 h0, h1, l0, l1;
#pragma unroll
        for (int i = 0; i < 8; ++i) {
            _Float16 h = (_Float16)av[i];
            h0[i] = h; l0[i] = (_Float16)(av[i] - (float)h);
        }
#pragma unroll
        for (int i = 0; i < 8; ++i) {
            _Float16 h = (_Float16)av[8 + i];
            h1[i] = h; l1[i] = (_Float16)(av[8 + i] - (float)h);
        }
        __syncthreads();   // prior tile's fragment reads complete
        *(f16x8*)&Ahs[ra][pa] = h0;  *(f16x8*)&Ahs[ra][pa + 8] = h1;
        *(f16x8*)&Als[ra][pa] = l0;  *(f16x8*)&Als[ra][pa + 8] = l1;
#pragma unroll
        for (int i = 0; i < 2; ++i) {
            int row0 = wid * 32 + i * 16;
            const _Float16* gh = Bh + (size_t)(bcol + row0 + rb) * K + k0 + cbk;
            __builtin_amdgcn_global_load_lds(
                (const __attribute__((address_space(1))) void*)gh,
                (__attribute__((address_space(3))) void*)&Bhs[row0][0], 16, 0, 0);
            const _Float16* gl = Bl + (size_t)(bcol + row0 + rb) * K + k0 + cbk;
            __builtin_amdgcn_global_load_lds(
                (const __attribute__((address_space(1))) void*)gl,
                (__attribute__((address_space(3))) void*)&Bls[row0][0], 16, 0, 0);
        }
        __syncthreads();   // staging visible

        f16x8 afh[4], afl[4], bfh[4], bfl[4];
#pragma unroll
        for (int m = 0; m < 4; ++m) {
            afh[m] = *(const f16x8*)&Ahs[wr + m * 16 + fr][fk];
            afl[m] = *(const f16x8*)&Als[wr + m * 16 + fr][fk];
        }
#pragma unroll
        for (int n = 0; n < 4; ++n) {
            bfh[n] = *(const f16x8*)&Bhs[wc + n * 16 + fr][fk];
            bfl[n] = *(const f16x8*)&Bls[wc + n * 16 + fr][fk];
        }
#pragma unroll
        for (int m = 0; m < 4; ++m)
#pragma unroll
            for (int n = 0; n < 4; ++n) {
                acc[m][n] = __builtin_amdgcn_mfma_f32_16x16x32_f16(afl[m], bfh[n], acc[m][n], 0, 0, 0);
                acc[m][n] = __builtin_amdgcn_mfma_f32_16x16x32_f16(afh[m], bfl[n], acc[m][n], 0, 0, 0);
                acc[m][n] = __builtin_amdgcn_mfma_f32_16x16x32_f16(afh[m], bfh[n], acc[m][n], 0, 0, 0);
            }
    }

    // epilogue: C/D layout col=lane&15, row=(lane>>4)*4+reg
#pragma unroll
    for (int m = 0; m < 4; ++m) {
        int row0 = brow + wr + m * 16 + crow;
#pragma unroll
        for (int n = 0; n < 4; ++n) {
            int col = bcol + wc + n * 16 + fr;
            float bv = bias1[col] + bias2[col];
#pragma unroll
            for (int r = 0; r < 4; ++r) {
                float v = acc[m][n][r] + bv;
                C[(size_t)(row0 + r) * N + col] = gelu_f(v);
            }
        }
    }
}

// ---------------- K2: route logits, N=64 ----------------
__global__ __launch_bounds__(256) void logits_k(const float* __restrict__ A,
                                                const float* __restrict__ Bw,
                                                const float* __restrict__ rb2,
                                                const float* __restrict__ taup,
                                                float* __restrict__ Cl,
                                                int M, int K) {
    __shared__ float As[16][64];
    __shared__ float Bs[16][64];
    const int tid = threadIdx.x;
    const int m0 = blockIdx.x * 64;
    const int tx = (tid & 15) * 4;
    const int ty = (tid >> 4) * 4;
    const int arow = tid >> 2;
    const int acol = (tid & 3) * 4;
    const int brl = tid >> 4;
    const int bcl = (tid & 15) * 4;

    float acc[4][4] = {};

    for (int k0 = 0; k0 < K; k0 += 16) {
        float4 av = *(const float4*)(A + (size_t)(m0 + arow) * K + k0 + acol);
        float4 bv = *(const float4*)(Bw + (size_t)(k0 + brl) * 64 + bcl);
        As[acol + 0][arow] = av.x;
        As[acol + 1][arow] = av.y;
        As[acol + 2][arow] = av.z;
        As[acol + 3][arow] = av.w;
        *(float4*)&Bs[brl][bcl] = bv;
        __syncthreads();
#pragma unroll
        for (int kk = 0; kk < 16; ++kk) {
            float a[4], b[4];
            *(float4*)&a[0] = *(const float4*)&As[kk][ty];
            *(float4*)&b[0] = *(const float4*)&Bs[kk][tx];
#pragma unroll
            for (int i = 0; i < 4; ++i)
#pragma unroll
                for (int j = 0; j < 4; ++j)
                    acc[i][j] = fmaf(a[i], b[j], acc[i][j]);
        }
        __syncthreads();
    }
    float inv = 1.0f / (fabsf(taup[0]) + 0.1f);
#pragma unroll
    for (int i = 0; i < 4; ++i)
#pragma unroll
        for (int j = 0; j < 4; ++j)
            Cl[(size_t)(m0 + ty + i) * 64 + tx + j] = (acc[i][j] + rb2[tx + j]) * inv;
}

// ---------------- K3: top-32-of-64 + softmax -> dense alpha (fp32 + f16 copy) --------
__global__ __launch_bounds__(256) void topk_k(const float* __restrict__ logits,
                                              float* __restrict__ alpha,
                                              _Float16* __restrict__ alpha16) {
    int wave = threadIdx.x >> 6;
    int lane = threadIdx.x & 63;
    int t = blockIdx.x * 4 + wave;
    float li = logits[(size_t)t * 64 + lane];
    float m = li;
#pragma unroll
    for (int off = 32; off; off >>= 1) m = fmaxf(m, __shfl_xor(m, off, 64));
    int cnt = 0;
    for (int off = 1; off < 64; ++off) {
        int j = (lane + off) & 63;
        float lj = __shfl(li, j, 64);
        cnt += (lj > li) || (lj == li && j < lane);
    }
    float e = (cnt < 32) ? expf(li - m) : 0.0f;
    float s = e;
#pragma unroll
    for (int off = 32; off; off >>= 1) s += __shfl_xor(s, off, 64);
    float a = e / s;
    alpha[(size_t)t * 64 + lane] = a;
    alpha16[(size_t)t * 64 + lane] = (_Float16)a;
}

// ---------------- K4: slot pooling (T-split partial sums) ----------------
__global__ __launch_bounds__(256) void pool_part_k(const float* __restrict__ x,
                                                   const float* __restrict__ alpha,
                                                   float* __restrict__ part,
                                                   float* __restrict__ partw) {
    int bh = blockIdx.x;
    int c = blockIdx.y;
    int b = bh >> 4, h = bh & 15;
    int tid = threadIdx.x;
    int s = tid >> 6, d = tid & 63;
    __shared__ float lx[16][64];
    __shared__ float la[16][4];
    float acc = 0.f, wacc = 0.f;
    const int tchunk = Tt / 8;
    const int t0base = c * tchunk;
    for (int t0 = 0; t0 < tchunk; t0 += 16) {
        int ttr = tid >> 4;
        int ddr = (tid & 15) * 4;
        size_t trow = (size_t)b * Tt + t0base + t0 + ttr;
        float4 xv = *(const float4*)(x + trow * Dd + h * 64 + ddr);
        *(float4*)&lx[ttr][ddr] = xv;
        if (tid < 64) {
            int tt2 = tid >> 2, ss = tid & 3;
            la[tt2][ss] = alpha[((size_t)b * Tt + t0base + t0 + tt2) * 64 + h * 4 + ss];
        }
        __syncthreads();
#pragma unroll
        for (int q = 0; q < 16; ++q) {
            float av = la[q][s];
            acc = fmaf(av, lx[q][d], acc);
            wacc += av;
        }
        __syncthreads();
    }
    part[(((size_t)c * 64 + bh) * 4 + s) * 64 + d] = acc;
    if (d == 0) partw[((size_t)c * 64 + bh) * 4 + s] = wacc;
}

__global__ __launch_bounds__(256) void pool_comb_k(const float* __restrict__ part,
                                                   const float* __restrict__ partw,
                                                   float* __restrict__ slot_in) {
    int bh = blockIdx.x;
    int tid = threadIdx.x;
    int s = tid >> 6, d = tid & 63;
    float acc = 0.f, w = 0.f;
    for (int c = 0; c < 8; ++c) {
        acc += part[(((size_t)c * 64 + bh) * 4 + s) * 64 + d];
        w   += partw[((size_t)c * 64 + bh) * 4 + s];
    }
    slot_in[((size_t)bh * 4 + s) * 64 + d] = acc / (w + 1e-8f);
}

// ---------------- K5: GRU + slot MLP, one wave per slot ----------------
__global__ __launch_bounds__(64) void gru_k(const float* __restrict__ slot_in,
                                            const float* __restrict__ slot_init,
                                            const float* __restrict__ gwi,
                                            const float* __restrict__ gwh,
                                            const float* __restrict__ gbi,
                                            const float* __restrict__ gbh,
                                            const float* __restrict__ hpw,
                                            const float* __restrict__ hpb,
                                            const float* __restrict__ ohw,
                                            const float* __restrict__ ohb,
                                            float* __restrict__ S_new) {
    int slot = blockIdx.x;
    int hs = slot & 63;
    int d = threadIdx.x;
    __shared__ float si[64], hp[64], hn[64], g[256];
    si[d] = slot_in[(size_t)slot * 64 + d];
    hp[d] = slot_init[(size_t)hs * 64 + d];
    __syncthreads();
    float gi_r = gbi[d], gi_z = gbi[64 + d], gi_n = gbi[128 + d];
    float gh_r = gbh[d], gh_z = gbh[64 + d], gh_n = gbh[128 + d];
    for (int k = 0; k < 64; ++k) {
        float sv = si[k], hv = hp[k];
        gi_r = fmaf(sv, gwi[(size_t)(d) * 64 + k], gi_r);
        gi_z = fmaf(sv, gwi[(size_t)(64 + d) * 64 + k], gi_z);
        gi_n = fmaf(sv, gwi[(size_t)(128 + d) * 64 + k], gi_n);
        gh_r = fmaf(hv, gwh[(size_t)(d) * 64 + k], gh_r);
        gh_z = fmaf(hv, gwh[(size_t)(64 + d) * 64 + k], gh_z);
        gh_n = fmaf(hv, gwh[(size_t)(128 + d) * 64 + k], gh_n);
    }
    float r = 1.0f / (1.0f + expf(-(gi_r + gh_r)));
    float z = 1.0f / (1.0f + expf(-(gi_z + gh_z)));
    float n = tanhf(gi_n + r * gh_n);
    float hnew = (1.0f - z) * n + z * hp[d];
    hn[d] = hnew;
    __syncthreads();
    float p0 = hpb[d], p1 = hpb[64 + d], p2 = hpb[128 + d], p3 = hpb[192 + d];
    for (int k = 0; k < 64; ++k) {
        float hv = hn[k];
        p0 = fmaf(hv, hpw[(size_t)k * 256 + d], p0);
        p1 = fmaf(hv, hpw[(size_t)k * 256 + 64 + d], p1);
        p2 = fmaf(hv, hpw[(size_t)k * 256 + 128 + d], p2);
        p3 = fmaf(hv, hpw[(size_t)k * 256 + 192 + d], p3);
    }
    g[d] = gelu_f(p0); g[64 + d] = gelu_f(p1); g[128 + d] = gelu_f(p2); g[192 + d] = gelu_f(p3);
    __syncthreads();
    float o = ohb[d];
    for (int j = 0; j < 256; ++j) o = fmaf(g[j], ohw[(size_t)j * 64 + d], o);
    S_new[(size_t)slot * 64 + d] = o;
}

// ---------------- K6: P^T[b][j][hs] = sum_d S_new[b,hs,d] * vpw[h*64+d, j]  (f16) ----
__global__ __launch_bounds__(256) void pmat_k(const float* __restrict__ Snew,
                                              const float* __restrict__ vpw,
                                              _Float16* __restrict__ PT) {
    int tid = threadIdx.x;
    int j = blockIdx.x * 64 + (tid & 63);
    int bq = tid >> 6;                       // batch 0..3 (one per wave)
    for (int hb = 0; hb < 8; ++hb) {
        float acc[8] = {};
        int h0 = hb * 2;
        for (int d = 0; d < 64; ++d) {
            float w0 = vpw[(size_t)(h0 * 64 + d) * HMm + j];
            float w1 = vpw[(size_t)((h0 + 1) * 64 + d) * HMm + j];
#pragma unroll
            for (int s = 0; s < 4; ++s) {
                acc[s]     = fmaf(Snew[((size_t)bq * 64 + h0 * 4 + s) * 64 + d], w0, acc[s]);
                acc[4 + s] = fmaf(Snew[((size_t)bq * 64 + (h0 + 1) * 4 + s) * 64 + d], w1, acc[4 + s]);
            }
        }
        f16x8 o;
#pragma unroll
        for (int i = 0; i < 8; ++i) o[i] = (_Float16)acc[i];
        *(f16x8*)&PT[((size_t)bq * 4096 + j) * 64 + hb * 8] = o;
    }
}

// ---------------- K7: transpose + fp32->fp16 convert: out[N,K] = (f16) in[K,N]^T -----
__global__ __launch_bounds__(256) void transp_f16_k(const float* __restrict__ in,
                                                    _Float16* __restrict__ out,
                                                    int K, int N) {
    __shared__ float t[32][33];
    int n0 = blockIdx.x * 32, k0 = blockIdx.y * 32;
    int tx = threadIdx.x & 31, ty = threadIdx.x >> 5;   // 32 x 8
#pragma unroll
    for (int i = 0; i < 32; i += 8)
        t[ty + i][tx] = in[(size_t)(k0 + ty + i) * N + n0 + tx];
    __syncthreads();
#pragma unroll
    for (int i = 0; i < 32; i += 8)
        out[(size_t)(n0 + ty + i) * K + k0 + tx] = (_Float16)t[tx][ty + i];
}

// ---------------- K8: fp16 MFMA GEMM: C = act(A[M,K] @ Bt[N,K]^T + bias) --------------
// 128x128 tile, BK=64, 4 waves, m97 structure (global_load_lds width 16, 2-barrier).
template <int DO_GELU, int OUT_F16>
__global__ __launch_bounds__(256) void hgemm_k(const _Float16* __restrict__ A,
                                               const _Float16* __restrict__ Bt,
                                               const float* __restrict__ bias,
                                               void* __restrict__ Cv,
                                               int M, int N, int K) {
    __shared__ __align__(16) _Float16 As[128][64];
    __shared__ __align__(16) _Float16 Bs[128][64];
    const int tid = threadIdx.x;
    const int wid = tid >> 6;
    const int lane = tid & 63;
    const int brow = blockIdx.y * 128;
    const int bcol = blockIdx.x * 128;
    const int wr = (wid >> 1) * 64;
    const int wc = (wid & 1) * 64;

    f32x4 acc[4][4];
#pragma unroll
    for (int m = 0; m < 4; ++m)
#pragma unroll
        for (int n = 0; n < 4; ++n)
            acc[m][n] = f32x4{0.f, 0.f, 0.f, 0.f};

    const int lrow = lane >> 3;          // 0..7
    const int lcol = (lane & 7) * 8;     // f16 elements

    const int fr = lane & 15;
    const int fk = (lane >> 4) * 8;

    for (int k0 = 0; k0 < K; k0 += 64) {
#pragma unroll
        for (int i = 0; i < 4; ++i) {
            int seg = wid * 4 + i;
            const _Float16* g = A + (size_t)(brow + seg * 8 + lrow) * K + k0 + lcol;
            __builtin_amdgcn_global_load_lds(
                (const __attribute__((address_space(1))) void*)g,
                (__attribute__((address_space(3))) void*)&As[seg * 8][0], 16, 0, 0);
        }
#pragma unroll
        for (int i = 0; i < 4; ++i) {
            int seg = wid * 4 + i;
            const _Float16* g = Bt + (size_t)(bcol + seg * 8 + lrow) * K + k0 + lcol;
            __builtin_amdgcn_global_load_lds(
                (const __attribute__((address_space(1))) void*)g,
                (__attribute__((address_space(3))) void*)&Bs[seg * 8][0], 16, 0, 0);
        }
        __syncthreads();
#pragma unroll
        for (int kb = 0; kb < 2; ++kb) {
            f16x8 af[4], bf[4];
#pragma unroll
            for (int m = 0; m < 4; ++m)
                af[m] = *(const f16x8*)&As[wr + m * 16 + fr][kb * 32 + fk];
#pragma unroll
            for (int n = 0; n < 4; ++n)
                bf[n] = *(const f16x8*)&Bs[wc + n * 16 + fr][kb * 32 + fk];
#pragma unroll
            for (int m = 0; m < 4; ++m)
#pragma unroll
                for (int n = 0; n < 4; ++n)
                    acc[m][n] = __builtin_amdgcn_mfma_f32_16x16x32_f16(af[m], bf[n], acc[m][n], 0, 0, 0);
        }
        __syncthreads();
    }

    const int crow = (lane >> 4) * 4;
#pragma unroll
    for (int m = 0; m < 4; ++m) {
        int row0 = brow + wr + m * 16 + crow;
#pragma unroll
        for (int n = 0; n < 4; ++n) {
            int col = bcol + wc + n * 16 + fr;
            float bv = bias ? bias[col] : 0.f;
#pragma unroll
            for (int r = 0; r < 4; ++r) {
                float v = acc[m][n][r] + bv;
                if (DO_GELU) v = gelu_f(v);
                size_t idx = (size_t)(row0 + r) * N + col;
                if (OUT_F16) ((_Float16*)Cv)[idx] = (_Float16)v;
                else ((float*)Cv)[idx] = v;
            }
        }
    }
}

extern "C" void kernel_launch(void* const* d_in, const int* in_sizes, int n_in,
                              void* d_out, int out_size, void* d_ws, size_t ws_size,
                              hipStream_t stream) {
    const float* x         = (const float*)d_in[0];
    const float* slot_init = (const float*)d_in[1];
    const float* rw1       = (const float*)d_in[2];
    const float* rb1       = (const float*)d_in[3];
    const float* rw2       = (const float*)d_in[4];
    const float* rb2       = (const float*)d_in[5];
    const float* gwi       = (const float*)d_in[6];
    const float* gwh       = (const float*)d_in[7];
    const float* gbi       = (const float*)d_in[8];
    const float* gbh       = (const float*)d_in[9];
    const float* hpw       = (const float*)d_in[10];
    const float* hpb       = (const float*)d_in[11];
    const float* ohw       = (const float*)d_in[12];
    const float* ohb       = (const float*)d_in[13];
    const float* vpw       = (const float*)d_in[14];
    const float* vpb       = (const float*)d_in[15];
    const float* vow       = (const float*)d_in[16];
    const float* vob       = (const float*)d_in[17];
    const float* opw       = (const float*)d_in[18];
    const float* opb       = (const float*)d_in[19];
    const float* tau       = (const float*)d_in[20];
    float* out = (float*)d_out;

    float* ws = (float*)d_ws;
    size_t off = 0;
    auto alloc = [&](size_t nfloats) { float* p = ws + off; off += (nfloats + 63) & ~(size_t)63; return p; };

    float* cb     = alloc(1024);
    float* h1     = alloc((size_t)MTOK * 1024);            // fp32; dead after logits:
    _Float16* v1cc = (_Float16*)h1;                         //   reused as v1 row-chunk [8192,4096] f16
    float* logits = alloc((size_t)MTOK * 64);
    float* alpha  = alloc((size_t)MTOK * 64);
    _Float16* alpha16 = (_Float16*)alloc((size_t)MTOK * 64 / 2);
    float* slotin = alloc(256 * 64);
    float* part   = alloc((size_t)8 * 64 * 4 * 64);
    float* partw  = alloc(8 * 64 * 4);
    float* Snew   = alloc(256 * 64);
    _Float16* PT   = (_Float16*)alloc((size_t)Bb * HMm * 64 / 2);  // [4,4096,64] f16
    _Float16* vowT = (_Float16*)alloc((size_t)Dd * HMm / 2);       // [1024,4096] f16
    _Float16* opwT = (_Float16*)alloc((size_t)Dd * Dd / 2);        // [1024,1024] f16
    _Float16* v2f16 = (_Float16*)alloc((size_t)MTOK * Dd / 2);     // [16384,1024] f16
    _Float16* w1hiT = (_Float16*)alloc((size_t)Dd * Dd / 2);       // [1024,1024] f16
    _Float16* w1loT = (_Float16*)alloc((size_t)Dd * Dd / 2);       // [1024,1024] f16

    // ---- routing: split-fp16 MFMA GEMM + fp32 logits ----
    cb_kernel<<<8, 128, 0, stream>>>(slot_init, rw1, cb);
    wsplitT_k<<<dim3(Dd / 32, Dd / 32), 256, 0, stream>>>(rw1, w1hiT, w1loT);
    hgemm3_k<<<dim3(Dd / 128, MTOK / 128), 256, 0, stream>>>(
        x, w1hiT, w1loT, rb1, cb, h1, MTOK, Dd, Dd);
    logits_k<<<MTOK / 64, 256, 0, stream>>>(h1, rw2, rb2, tau, logits, MTOK, 1024);
    topk_k<<<MTOK / 4, 256, 0, stream>>>(logits, alpha, alpha16);

    // ---- weight transposes (fp32 -> fp16 [N,K]) ----
    transp_f16_k<<<dim3(Dd / 32, HMm / 32), 256, 0, stream>>>(vow, vowT, HMm, Dd);
    transp_f16_k<<<dim3(Dd / 32, Dd / 32), 256, 0, stream>>>(opw, opwT, Dd, Dd);

    // ---- slot pooling + GRU + slot MLP ----
    pool_part_k<<<dim3(64, 8), 256, 0, stream>>>(x, alpha, part, partw);
    pool_comb_k<<<64, 256, 0, stream>>>(part, partw, slotin);
    gru_k<<<256, 64, 0, stream>>>(slotin, slot_init, gwi, gwh, gbi, gbh,
                                  hpw, hpb, ohw, ohb, Snew);

    // ---- P^T[b] = (S_emb[b] @ vpw)^T : rank-64 structure kills GEMM1 ----
    pmat_k<<<HMm / 64, 256, 0, stream>>>(Snew, vpw, PT);

    // ---- value MLP: v1 = gelu(alpha @ P[b] + vpb) via K=64 MFMA GEMM, then GEMM2 ----
    for (int c = 0; c < 2; ++c) {
        for (int q = 0; q < 2; ++q) {
            int b = c * 2 + q;
            hgemm_k<1, 1><<<dim3(HMm / 128, Tt / 128), 256, 0, stream>>>(
                alpha16 + (size_t)b * Tt * 64, PT + (size_t)b * HMm * 64, vpb,
                v1cc + (size_t)q * Tt * HMm, Tt, HMm, 64);
        }
        hgemm_k<0, 1><<<dim3(Dd / 128, 8192 / 128), 256, 0, stream>>>(
            v1cc, vowT, vob, v2f16 + (size_t)c * 8192 * Dd, 8192, Dd, HMm);
    }
    // ---- final projection (fp32 out) ----
    hgemm_k<0, 0><<<dim3(Dd / 128, MTOK / 128), 256, 0, stream>>>(
        v2f16, opwT, opb, out, MTOK, Dd, Dd);

    (void)in_sizes; (void)n_in; (void)out_size; (void)ws_size;
}